// Round 10
// baseline (204.120 us; speedup 1.0000x reference)
//
#include <hip/hip_runtime.h>
#include <hip/hip_bf16.h>

#define NB 4
#define NC 512
#define NN 4096
#define NM 640
#define LOG2E 1.4426950408889634f

typedef __attribute__((ext_vector_type(8))) short bf16x8;
typedef __attribute__((ext_vector_type(4))) float f32x4;

__device__ __forceinline__ f32x4 mfma16(bf16x8 a, bf16x8 b, f32x4 c) {
  return __builtin_amdgcn_mfma_f32_16x16x32_bf16(a, b, c, 0, 0, 0);
}

__device__ __forceinline__ unsigned short f2bf(float f) {
  unsigned int u = __float_as_uint(f);
  u += 0x7fffu + ((u >> 16) & 1u);   // round-to-nearest-even
  return (unsigned short)(u >> 16);
}

typedef const __attribute__((address_space(1))) char gchar_t;
typedef __attribute__((address_space(3))) char lchar_t;

// ---------------- pack weights: W[640][512] bf16 + bias[640] f32 ----------------
__global__ void pack_w(const float* __restrict__ wq, const float* __restrict__ bq,
                       const float* __restrict__ wk, const float* __restrict__ bk,
                       const float* __restrict__ wv, const float* __restrict__ bv,
                       unsigned short* __restrict__ W, float* __restrict__ bias) {
  int idx = blockIdx.x * 256 + threadIdx.x;
  if (idx < NM * NC) {
    int r = idx >> 9, c = idx & (NC - 1);
    float v;
    if (r < 64) v = wq[r * NC + c];
    else if (r < 128) v = wk[(r - 64) * NC + c];
    else v = wv[(r - 128) * NC + c];
    W[idx] = f2bf(v);
  }
  if (idx < NM)
    bias[idx] = (idx < 64) ? bq[idx] : (idx < 128 ? bk[idx - 64] : bv[idx - 128]);
}

// ---------------- transpose + convert: x[b][c][n] f32 -> XT[b][n][c] bf16 ----------------
__global__ void xpose(const float* __restrict__ x, unsigned short* __restrict__ XT) {
  __shared__ float t[64][65];
  int b = blockIdx.z;
  int c0 = blockIdx.y * 64, n0 = blockIdx.x * 64;
  int tx = threadIdx.x & 63, ty = threadIdx.x >> 6;  // 256 threads
  const float* xb = x + (size_t)b * NC * NN;
#pragma unroll
  for (int i = 0; i < 16; ++i) {
    int c = i * 4 + ty;
    t[c][tx] = xb[(size_t)(c0 + c) * NN + n0 + tx];
  }
  __syncthreads();
  unsigned short* xtb = XT + (size_t)b * NN * NC;
#pragma unroll
  for (int i = 0; i < 16; ++i) {
    int n = i * 4 + ty;
    xtb[(size_t)(n0 + n) * NC + c0 + tx] = f2bf(t[tx][n]);
  }
}

// ---------------- QKV projection GEMM (NT): C[m][n] = sum_k W[m][k]*XT[n][k] ----------------
__global__ __launch_bounds__(512) void gemm_qkv(
    const unsigned short* __restrict__ W, const float* __restrict__ bias,
    const unsigned short* __restrict__ XT,
    unsigned short* __restrict__ QT, unsigned short* __restrict__ KT,
    unsigned short* __restrict__ V) {
  int b = blockIdx.z;
  int m0 = blockIdx.y * 80;
  int wave = threadIdx.x >> 6, lane = threadIdx.x & 63;
  int nw = blockIdx.x * 512 + wave * 64;
  int lcol = lane & 15, lkg = lane >> 4;
  const unsigned short* xtb = XT + (size_t)b * NN * NC;
  f32x4 acc[5][4] = {};
  for (int k0 = 0; k0 < NC; k0 += 32) {
    int ko = k0 + lkg * 8;
    bf16x8 afr[5], bfr[4];
#pragma unroll
    for (int i = 0; i < 5; ++i)
      afr[i] = *reinterpret_cast<const bf16x8*>(W + (size_t)(m0 + 16 * i + lcol) * NC + ko);
#pragma unroll
    for (int j = 0; j < 4; ++j)
      bfr[j] = *reinterpret_cast<const bf16x8*>(xtb + (size_t)(nw + 16 * j + lcol) * NC + ko);
#pragma unroll
    for (int i = 0; i < 5; ++i)
#pragma unroll
      for (int j = 0; j < 4; ++j)
        acc[i][j] = mfma16(afr[i], bfr[j], acc[i][j]);
  }
  int rbase = lkg * 4;
#pragma unroll
  for (int i = 0; i < 5; ++i) {
    int mrow = m0 + 16 * i;
    if (mrow < 128) {
      bool isq = mrow < 64;
      unsigned short* T = isq ? (QT + (size_t)b * NN * 64) : (KT + (size_t)b * NN * 64);
      int mb = mrow & 63;
      float sc = isq ? LOG2E : 1.0f;
#pragma unroll
      for (int j = 0; j < 4; ++j) {
        int n = nw + 16 * j + lcol;
        union { unsigned short h[4]; unsigned long long u; } pk;
#pragma unroll
        for (int r = 0; r < 4; ++r)
          pk.h[r] = f2bf((acc[i][j][r] + bias[mrow + rbase + r]) * sc);
        *reinterpret_cast<unsigned long long*>(T + (size_t)n * 64 + mb + rbase) = pk.u;
      }
    } else {
      unsigned short* vb = V + (size_t)b * NC * NN;
#pragma unroll
      for (int r = 0; r < 4; ++r) {
        int m = mrow + rbase + r;
        float bs = bias[m];
        int c = m - 128;
#pragma unroll
        for (int j = 0; j < 4; ++j) {
          int n = nw + 16 * j + lcol;
          vb[(size_t)c * NN + n] = f2bf(acc[i][j][r] + bs);
        }
      }
    }
  }
}

// ---------------- attention stats: exact m_j, l_j per column (log2 domain) ----------------
// grid 512 = (b XCD-pair, jb 0..127 of 32 j), 256 threads (4 waves) -> 2 blocks/CU.
__global__ __launch_bounds__(256, 4) void attn_stats(
    const unsigned short* __restrict__ QT, const unsigned short* __restrict__ KT,
    float* __restrict__ Mst, float* __restrict__ Lst) {
  int bid = blockIdx.x;
  int b = (bid & 7) >> 1;
  int jb = ((bid >> 3) << 1) | (bid & 1);   // 0..127
  int j0 = jb * 32;
  int wave = threadIdx.x >> 6, lane = threadIdx.x & 63;
  int lcol = lane & 15, lkg = lane >> 4;

  __shared__ float sm[32][5], sl[32][5];

  const unsigned short* qt = QT + (size_t)b * NN * 64;
  const unsigned short* kt = KT + (size_t)b * NN * 64;

  bf16x8 kfr[2][2];
#pragma unroll
  for (int fn = 0; fn < 2; ++fn)
#pragma unroll
    for (int ks = 0; ks < 2; ++ks)
      kfr[fn][ks] = *reinterpret_cast<const bf16x8*>(
          kt + (size_t)(j0 + 16 * fn + lcol) * 64 + ks * 32 + lkg * 8);

  float m_l[2], l_l[2];
#pragma unroll
  for (int fn = 0; fn < 2; ++fn) { m_l[fn] = -1e30f; l_l[fn] = 0.f; }

  bf16x8 qfr[2];
#pragma unroll
  for (int ks = 0; ks < 2; ++ks)
    qfr[ks] = *reinterpret_cast<const bf16x8*>(
        qt + (size_t)(wave * 16 + lcol) * 64 + ks * 32 + lkg * 8);

  for (int it = 0; it < 64; ++it) {
    f32x4 s[2] = {};
#pragma unroll
    for (int ks = 0; ks < 2; ++ks)
#pragma unroll
      for (int fn = 0; fn < 2; ++fn)
        s[fn] = mfma16(qfr[ks], kfr[fn][ks], s[fn]);
    if (it + 1 < 64) {
      int ib = ((it + 1) * 4 + wave) * 16;
#pragma unroll
      for (int ks = 0; ks < 2; ++ks)
        qfr[ks] = *reinterpret_cast<const bf16x8*>(
            qt + (size_t)(ib + lcol) * 64 + ks * 32 + lkg * 8);
    }
#pragma unroll
    for (int fn = 0; fn < 2; ++fn) {
      float mx = fmaxf(fmaxf(s[fn][0], s[fn][1]), fmaxf(s[fn][2], s[fn][3]));
      float nm = fmaxf(m_l[fn], mx);
      float ps = 0.f;
#pragma unroll
      for (int r = 0; r < 4; ++r) ps += exp2f(s[fn][r] - nm);
      l_l[fn] = l_l[fn] * exp2f(m_l[fn] - nm) + ps;
      m_l[fn] = nm;
    }
  }

#pragma unroll
  for (int fn = 0; fn < 2; ++fn) {
#pragma unroll
    for (int off = 16; off <= 32; off <<= 1) {
      float om = __shfl_xor(m_l[fn], off), ol = __shfl_xor(l_l[fn], off);
      float nm = fmaxf(m_l[fn], om);
      l_l[fn] = l_l[fn] * exp2f(m_l[fn] - nm) + ol * exp2f(om - nm);
      m_l[fn] = nm;
    }
    if (lkg == 0) { sm[16 * fn + lcol][wave] = m_l[fn]; sl[16 * fn + lcol][wave] = l_l[fn]; }
  }
  __syncthreads();
  if (wave == 0 && lane < 32) {
    int j = lane;
    float m = -1e30f, l = 0.f;
#pragma unroll
    for (int w = 0; w < 4; ++w) {
      float om = sm[j][w], ol = sl[j][w];
      float nm = fmaxf(m, om);
      l = l * exp2f(m - nm) + ol * exp2f(om - nm);
      m = nm;
    }
    Mst[(size_t)b * NN + j0 + j] = m;
    Lst[(size_t)b * NN + j0 + j] = l;
  }
}

// ---------------- attention PV: producer/consumer waves, 2 blocks/CU ----------------
// grid 512 = 4b x 64jb x 2 c-halves (bid&1 -> own XCD). 512 thr. IB=32, 128 iters.
// Waves 0-3 CONSUMERS: stage own 64 c-rows of V(t+1) via global_load_lds (paired-row
//   swizzled layout), vmcnt(4), 16 PV MFMA from LDS. oacc 64c x 64j.
// Waves 4-7 PRODUCERS: QK^T(t+1) (16i x 32j each), exp2, P^T -> 80B-row LDS.
// One barrier/iter; separate loops keep register sets disjoint.
__global__ __launch_bounds__(512, 4) void attn_pv(
    const unsigned short* __restrict__ QT, const unsigned short* __restrict__ KT,
    const unsigned short* __restrict__ V, const float* __restrict__ x,
    const float* __restrict__ gamma, const float* __restrict__ Mst,
    const float* __restrict__ Lst, float* __restrict__ out) {
  int bid = blockIdx.x;
  int b = (bid & 7) >> 1;        // batch -> XCD pair {2b,2b+1}
  int ch = bid & 1;              // c-half -> one XCD of the pair
  int jb = bid >> 3;             // 0..63
  int j0 = jb * 64;
  int wave = threadIdx.x >> 6, lane = threadIdx.x & 63;
  int lcol = lane & 15, lkg = lane >> 4;

  // V: paired-row layout [128 LDS-rows x 128B], unit swizz u_phys = u_log ^ (row&7)
  __shared__ __align__(16) unsigned short vlds[2][128 * 64];  // 32 KB
  // P^T: [64 j][80 B] padded rows (conflict-free b128 reads)
  __shared__ __align__(16) unsigned short plds[2][64 * 40];   // 10 KB

  const unsigned short* qt = QT + (size_t)b * NN * 64;
  const unsigned short* kt = KT + (size_t)b * NN * 64;
  const unsigned short* vp = V + (size_t)b * NC * NN;

  if (wave < 4) {
    // ================= CONSUMER =================
    const int lrow = lane >> 3;            // 0..7
    const int ulog = (lane & 7) ^ lrow;    // logical unit at this lane's dest
    auto stage = [&](int itv) {
      int i0 = (itv & 127) * 32;
      lchar_t* lb = (lchar_t*)vlds + (size_t)(itv & 1) * 16384 + wave * 4096;
#pragma unroll
      for (int q = 0; q < 4; ++q) {
        int cl = ch * 256 + wave * 64 + 2 * (q * 8 + lrow) + (ulog >> 2);
        const unsigned short* gp = vp + (size_t)cl * NN + i0 + (ulog & 3) * 8;
        __builtin_amdgcn_global_load_lds((gchar_t*)gp, lb + q * 1024, 16, 0, 0);
      }
    };

    float lj[4];
#pragma unroll
    for (int fn = 0; fn < 4; ++fn)
      lj[fn] = Lst[(size_t)b * NN + j0 + 16 * fn + lcol];

    f32x4 oacc[4][4] = {};  // [cm][fn]

    stage(0);
    asm volatile("s_waitcnt lgkmcnt(0)" ::: "memory");
    __builtin_amdgcn_s_barrier();   // matches producer prologue barrier

    for (int t = 0; t < 128; ++t) {
      stage(t + 1);
      const char* pb = (const char*)plds + (t & 1) * 5120;
      const char* vbuf = (const char*)vlds + (t & 1) * 16384 + wave * 4096;
      asm volatile("s_waitcnt vmcnt(4)" ::: "memory");  // stage(t) landed
      __builtin_amdgcn_s_setprio(1);
      bf16x8 pfr[4];
#pragma unroll
      for (int fn = 0; fn < 4; ++fn)
        pfr[fn] = *reinterpret_cast<const bf16x8*>(pb + (16 * fn + lcol) * 80 + lkg * 16);
#pragma unroll
      for (int cm = 0; cm < 4; ++cm) {
        int Rl = 8 * cm + (lcol >> 1);
        int up = ((lcol & 1) * 4 + lkg) ^ (lcol >> 1);
        bf16x8 vfr = *reinterpret_cast<const bf16x8*>(vbuf + Rl * 128 + up * 16);
#pragma unroll
        for (int fn = 0; fn < 4; ++fn)
          oacc[cm][fn] = mfma16(vfr, pfr[fn], oacc[cm][fn]);
      }
      __builtin_amdgcn_s_setprio(0);
      asm volatile("s_waitcnt lgkmcnt(0)" ::: "memory");
      __builtin_amdgcn_s_barrier();
      asm volatile("" ::: "memory");
    }

    // epilogue: out = gamma * O/l + x
    float g = gamma[0];
    const float* xb = x + (size_t)b * NC * NN;
    float* ob = out + (size_t)b * NC * NN;
#pragma unroll
    for (int fn = 0; fn < 4; ++fn) {
      float sc = g / lj[fn];
      int j = j0 + 16 * fn + lcol;
#pragma unroll
      for (int cm = 0; cm < 4; ++cm) {
        int c = ch * 256 + wave * 64 + 16 * cm + lkg * 4;
#pragma unroll
        for (int r = 0; r < 4; ++r) {
          size_t idx = (size_t)(c + r) * NN + j;
          ob[idx] = oacc[cm][fn][r] * sc + xb[idx];
        }
      }
    }
  } else {
    // ================= PRODUCER =================
    int pw = wave - 4;
    int sw = pw & 1;       // i-strip (16 rows)
    int fnp = pw >> 1;     // fn pair: fn = 2*fnp + {0,1}
    bf16x8 kfrP[2][2];
    float ml2[2];
#pragma unroll
    for (int f = 0; f < 2; ++f) {
      int fn = 2 * fnp + f;
#pragma unroll
      for (int ks = 0; ks < 2; ++ks)
        kfrP[f][ks] = *reinterpret_cast<const bf16x8*>(
            kt + (size_t)(j0 + 16 * fn + lcol) * 64 + ks * 32 + lkg * 8);
      ml2[f] = Mst[(size_t)b * NN + j0 + 16 * fn + lcol];  // log2-domain
    }

    bf16x8 qA[2], qB[2];
    {
      int row = sw * 16 + lcol;  // i-block 0
      qA[0] = *reinterpret_cast<const bf16x8*>(qt + (size_t)row * 64 + lkg * 8);
      qA[1] = *reinterpret_cast<const bf16x8*>(qt + (size_t)row * 64 + 32 + lkg * 8);
    }
    // prologue: P(0) -> plds[0]
    {
      f32x4 s0 = {}, s1 = {};
      s0 = mfma16(qA[0], kfrP[0][0], s0); s0 = mfma16(qA[1], kfrP[0][1], s0);
      s1 = mfma16(qA[0], kfrP[1][0], s1); s1 = mfma16(qA[1], kfrP[1][1], s1);
      char* pwr = (char*)plds;
      union { unsigned short h[4]; unsigned long long u; } pk;
#pragma unroll
      for (int r = 0; r < 4; ++r) pk.h[r] = f2bf(exp2f(s0[r] - ml2[0]));
      *reinterpret_cast<unsigned long long*>(
          pwr + (16 * (2 * fnp) + lcol) * 80 + sw * 32 + lkg * 8) = pk.u;
#pragma unroll
      for (int r = 0; r < 4; ++r) pk.h[r] = f2bf(exp2f(s1[r] - ml2[1]));
      *reinterpret_cast<unsigned long long*>(
          pwr + (16 * (2 * fnp + 1) + lcol) * 80 + sw * 32 + lkg * 8) = pk.u;
    }
    {
      int row = 32 + sw * 16 + lcol;  // i-block 1
      qB[0] = *reinterpret_cast<const bf16x8*>(qt + (size_t)row * 64 + lkg * 8);
      qB[1] = *reinterpret_cast<const bf16x8*>(qt + (size_t)row * 64 + 32 + lkg * 8);
    }
    asm volatile("s_waitcnt lgkmcnt(0)" ::: "memory");
    __builtin_amdgcn_s_barrier();

#define PROD_ITER(IT, QC, QN)                                                    \
    {                                                                            \
      const int t_ = (IT);                                                       \
      f32x4 s0 = {}, s1 = {};                                                    \
      s0 = mfma16(QC[0], kfrP[0][0], s0); s0 = mfma16(QC[1], kfrP[0][1], s0);    \
      s1 = mfma16(QC[0], kfrP[1][0], s1); s1 = mfma16(QC[1], kfrP[1][1], s1);    \
      int rown = ((t_ + 2) & 127) * 32 + sw * 16 + lcol;                         \
      QN[0] = *reinterpret_cast<const bf16x8*>(qt + (size_t)rown * 64 + lkg * 8);\
      QN[1] = *reinterpret_cast<const bf16x8*>(qt + (size_t)rown * 64 + 32 + lkg * 8); \
      char* pwr = (char*)plds + ((t_ + 1) & 1) * 5120;                           \
      union { unsigned short h[4]; unsigned long long u; } pk;                   \
      _Pragma("unroll") for (int r = 0; r < 4; ++r)                              \
        pk.h[r] = f2bf(exp2f(s0[r] - ml2[0]));                                   \
      *reinterpret_cast<unsigned long long*>(                                    \
          pwr + (16 * (2 * fnp) + lcol) * 80 + sw * 32 + lkg * 8) = pk.u;        \
      _Pragma("unroll") for (int r = 0; r < 4; ++r)                              \
        pk.h[r] = f2bf(exp2f(s1[r] - ml2[1]));                                   \
      *reinterpret_cast<unsigned long long*>(                                    \
          pwr + (16 * (2 * fnp + 1) + lcol) * 80 + sw * 32 + lkg * 8) = pk.u;    \
      asm volatile("s_waitcnt lgkmcnt(0)" ::: "memory");                         \
      __builtin_amdgcn_s_barrier();                                              \
      asm volatile("" ::: "memory");                                             \
    }

    for (int t2 = 0; t2 < 128; t2 += 2) {
      PROD_ITER(t2 + 0, qB, qA);   // S(t+1): t2+1 uses qB (i-block 1 at t2=0)
      PROD_ITER(t2 + 1, qA, qB);
    }
#undef PROD_ITER
  }
}

extern "C" void kernel_launch(void* const* d_in, const int* in_sizes, int n_in,
                              void* d_out, int out_size, void* d_ws, size_t ws_size,
                              hipStream_t stream) {
  const float* x  = (const float*)d_in[0];
  const float* wq = (const float*)d_in[1];
  const float* bq = (const float*)d_in[2];
  const float* wk = (const float*)d_in[3];
  const float* bk = (const float*)d_in[4];
  const float* wv = (const float*)d_in[5];
  const float* bv = (const float*)d_in[6];
  const float* gm = (const float*)d_in[7];
  float* out = (float*)d_out;

  char* ws = (char*)d_ws;
  unsigned short* XT = (unsigned short*)(ws);                             // 16 MB
  unsigned short* Vb = (unsigned short*)(ws + (size_t)16 * 1024 * 1024);  // 16 MB
  unsigned short* QT = (unsigned short*)(ws + (size_t)32 * 1024 * 1024);  // 2 MB
  unsigned short* KT = (unsigned short*)(ws + (size_t)34 * 1024 * 1024);  // 2 MB
  unsigned short* Wp = (unsigned short*)(ws + (size_t)36 * 1024 * 1024);  // 640 KB
  float* biasp = (float*)(ws + (size_t)36 * 1024 * 1024 + 704 * 1024);    // 2.5 KB
  float* Mst   = (float*)(ws + (size_t)36 * 1024 * 1024 + 768 * 1024);    // 64 KB
  float* Lst   = (float*)(ws + (size_t)36 * 1024 * 1024 + 832 * 1024);    // 64 KB

  pack_w<<<(NM * NC + 255) / 256, 256, 0, stream>>>(wq, bq, wk, bk, wv, bv, Wp, biasp);
  xpose<<<dim3(NN / 64, NC / 64, NB), 256, 0, stream>>>(x, XT);
  gemm_qkv<<<dim3(NN / 512, NM / 80, NB), 512, 0, stream>>>(Wp, biasp, XT, QT, KT, Vb);
  attn_stats<<<512, 256, 0, stream>>>(QT, KT, Mst, Lst);
  attn_pv<<<512, 512, 0, stream>>>(QT, KT, Vb, x, gm, Mst, Lst, out);
}